// Round 7
// baseline (75.062 us; speedup 1.0000x reference)
//
#include <hip/hip_runtime.h>
#include <stdint.h>

#define BATCH 16384
#define NF 768
#define FT 1024
#define RB 32               // batch rows per block
#define GR (2 * RB)         // GEMM rows per block (stm 0-31, nstm 32-63)
#define THREADS 1024
#define NW 16
#define ALD 784             // A-LDS row stride bytes (768 + 16 pad, 2-way=free)
#define NKS 12              // 768 / 64 K-steps

typedef int i32x4 __attribute__((ext_vector_type(4)));

// ---- prep: W_ft [FT][NF] f32 -> Wq [FT][NF] i8 (per-row scale 127/absmax) --
__global__ __launch_bounds__(192) void prep_wq(const float* __restrict__ W_ft,
                                               char* __restrict__ Wq,
                                               float* __restrict__ invs) {
    const int o = blockIdx.x;
    const int t = threadIdx.x;
    __shared__ float smax[3];
    __shared__ float sscale;
    const float4 v = *(const float4*)(W_ft + (size_t)o * NF + t * 4);
    float m = fmaxf(fmaxf(fabsf(v.x), fabsf(v.y)), fmaxf(fabsf(v.z), fabsf(v.w)));
    #pragma unroll
    for (int s = 32; s > 0; s >>= 1) m = fmaxf(m, __shfl_down(m, s, 64));
    if ((t & 63) == 0) smax[t >> 6] = m;
    __syncthreads();
    if (t == 0) {
        const float am = fmaxf(fmaxf(smax[0], smax[1]), smax[2]);
        sscale = 127.0f / am;
        invs[o] = am / 127.0f;
    }
    __syncthreads();
    const float s = sscale;
    const float arr[4] = {v.x, v.y, v.z, v.w};
    uint32_t pk = 0;
    #pragma unroll
    for (int j = 0; j < 4; ++j) {
        const int q = (int)rintf(arr[j] * s);
        pk |= ((uint32_t)(unsigned char)(char)q) << (8 * j);
    }
    *(uint32_t*)(Wq + (size_t)o * NF + t * 4) = pk;
}

__device__ __forceinline__ uint32_t pack01(float4 v) {
    return (uint32_t)(v.x != 0.0f) | ((uint32_t)(v.y != 0.0f) << 8)
         | ((uint32_t)(v.z != 0.0f) << 16) | ((uint32_t)(v.w != 0.0f) << 24);
}

// ---- fused dense i8-MFMA FT + SCReLU + output layer + sigmoid --------------
// 16 waves; wave w owns cols [64w, 64w+64) x all 64 GEMM rows (acc[4][4]).
// A staged fully up front (ONE barrier); K-loop is barrier-free so the 4
// waves/SIMD slip freely and the compiler pipelines B loads across iters.
__global__ __launch_bounds__(THREADS, 4) void nnue_mfma(
    const float* __restrict__ bstm, const float* __restrict__ bnstm,
    const char* __restrict__ Wq, const float* __restrict__ invs,
    const float* __restrict__ b_ft, const float* __restrict__ W_out,
    const float* __restrict__ b_out, float* __restrict__ out)
{
    __shared__ __align__(16) char Albs[GR * ALD];   // 50176 B
    __shared__ float red[GR][NW];                   // 4096 B

    const int t = threadIdx.x;
    const int w = t >> 6;
    const int l = t & 63;
    const int b0 = blockIdx.x * RB;

    // Phase 1: stage boards -> i8 {0,1} in LDS. 12288 u32 writes, 12/thread.
    // Load all 12 float4 first (independent -> overlapped L3 latency).
    float4 sv[12];
    int srow[12], sc4[12];
    #pragma unroll
    for (int it = 0; it < 12; ++it) {
        const int g = it * THREADS + t;
        const int row = g / 192;
        const int c4 = g - row * 192;
        const float* src = (row < RB) ? (bstm + (size_t)(b0 + row) * NF)
                                      : (bnstm + (size_t)(b0 + row - RB) * NF);
        sv[it] = *(const float4*)(src + c4 * 4);
        srow[it] = row; sc4[it] = c4;
    }
    #pragma unroll
    for (int it = 0; it < 12; ++it)
        *(uint32_t*)(&Albs[srow[it] * ALD + sc4[it] * 4]) = pack01(sv[it]);
    __syncthreads();

    // Phase 2: barrier-free K-loop.
    // A: lane holds A[row=l&15][k=(l>>4)*16+j]; B: lane holds
    // B[k=(l>>4)*16+j][col=l&15] = 16 contiguous bytes of Wq[col][.].
    const int cl = l & 15;
    const int q = l >> 4;
    const char* bptr = Wq + (size_t)(w * 64 + cl) * NF + q * 16;
    const int aoff = cl * ALD + q * 16;

    i32x4 acc[4][4] = {};
    #pragma unroll 2
    for (int ks = 0; ks < NKS; ++ks) {
        i32x4 bfrag[4];
        #pragma unroll
        for (int c = 0; c < 4; ++c)
            bfrag[c] = *(const i32x4*)(bptr + (size_t)c * 16 * NF + ks * 64);
        i32x4 afrag[4];
        #pragma unroll
        for (int r = 0; r < 4; ++r)
            afrag[r] = *(const i32x4*)(&Albs[aoff + r * 16 * ALD + ks * 64]);
        #pragma unroll
        for (int r = 0; r < 4; ++r)
            #pragma unroll
            for (int c = 0; c < 4; ++c)
                acc[r][c] = __builtin_amdgcn_mfma_i32_16x16x64_i8(
                    afrag[r], bfrag[c], acc[r][c], 0, 0, 0);
    }

    // Phase 3: epilogue. C/D lane mapping col=l&15, row=(l>>4)*4+j.
    float ps[4][4] = {};
    #pragma unroll
    for (int c = 0; c < 4; ++c) {
        const int col = w * 64 + c * 16 + cl;
        const float iv = invs[col];
        const float bf = b_ft[col];
        const float wo0 = W_out[col];
        const float wo1 = W_out[FT + col];
        #pragma unroll
        for (int r = 0; r < 4; ++r) {
            const float wo = (r < 2) ? wo0 : wo1;   // rows 0-31 stm, 32-63 nstm
            #pragma unroll
            for (int j = 0; j < 4; ++j) {
                float h = fmaf((float)acc[r][c][j], iv, bf);
                h = fminf(fmaxf(h, 0.0f), 1.0f);
                ps[r][j] = fmaf(h * h, wo, ps[r][j]);
            }
        }
    }
    #pragma unroll
    for (int r = 0; r < 4; ++r)
        #pragma unroll
        for (int j = 0; j < 4; ++j) {
            float v = ps[r][j];
            v += __shfl_xor(v, 1, 64);
            v += __shfl_xor(v, 2, 64);
            v += __shfl_xor(v, 4, 64);
            v += __shfl_xor(v, 8, 64);
            if (cl == 0) red[16 * r + 4 * q + j][w] = v;
        }
    __syncthreads();

    // Phase 4: per batch row, sum stm(t) + nstm(32+t) over 16 waves.
    if (t < RB) {
        float x = b_out[0];
        #pragma unroll
        for (int w2 = 0; w2 < NW; ++w2)
            x += red[t][w2] + red[RB + t][w2];
        out[b0 + t] = 1.0f / (1.0f + expf(-x));
    }
}

extern "C" void kernel_launch(void* const* d_in, const int* in_sizes, int n_in,
                              void* d_out, int out_size, void* d_ws, size_t ws_size,
                              hipStream_t stream) {
    const float* board_stm  = (const float*)d_in[0];
    const float* board_nstm = (const float*)d_in[1];
    const float* W_ft       = (const float*)d_in[2];
    const float* b_ft       = (const float*)d_in[3];
    const float* W_out      = (const float*)d_in[4];
    const float* b_out      = (const float*)d_in[5];
    float* out = (float*)d_out;

    char* Wq = (char*)d_ws;                                // FT*NF i8 = 768 KB
    float* invs = (float*)((char*)d_ws + (size_t)FT * NF); // 4 KB

    prep_wq<<<FT, 192, 0, stream>>>(W_ft, Wq, invs);
    nnue_mfma<<<BATCH / RB, THREADS, 0, stream>>>(board_stm, board_nstm, Wq, invs,
                                                  b_ft, W_out, b_out, out);
}